// Round 13
// baseline (868.960 us; speedup 1.0000x reference)
//
#include <hip/hip_runtime.h>

#define NN 50000
#define NE 600000
#define HD 128
#define NL 4
#define NSCB 196    // ceil(NN/256)
#define NTILE 9375  // NE/64
#define NWG_E2 4688 // ceil(NTILE/2) = 8*586 (XCD-exact)

typedef __bf16 bf16x8 __attribute__((ext_vector_type(8)));
typedef float f32x4 __attribute__((ext_vector_type(4)));

__device__ __forceinline__ unsigned short f2bf(float x){
  union { float f; unsigned int u; } v; v.f = x;
  unsigned int r = v.u + 0x7FFFu + ((v.u >> 16) & 1u);
  return (unsigned short)(r >> 16);
}
// silu via raw trans ops: avoids precise-div expansion
__device__ __forceinline__ float silu_f(float x){
  float e, r;
  float t = x * -1.44269504088896340736f;
  asm("v_exp_f32 %0, %1" : "=v"(e) : "v"(t));
  float d = 1.f + e;
  asm("v_rcp_f32 %0, %1" : "=v"(r) : "v"(d));
  return x * r;
}
__device__ __forceinline__ unsigned pk_bf16(float v0, float v1){
  unsigned r;
  asm("v_cvt_pk_bf16_f32 %0, %1, %2" : "=v"(r) : "v"(v0), "v"(v1));
  return r;
}
// packed bf16x2 atomic add (gfx950 GLOBAL_ATOMIC_PK_ADD_BF16), no return
__device__ __forceinline__ void atomic_pk_add_bf16(unsigned short* addr, unsigned data){
  asm volatile("global_atomic_pk_add_bf16 %0, %1, off"
    :: "v"((unsigned long long)(uintptr_t)addr), "v"(data) : "memory");
}

__device__ __forceinline__ f32x4 mfma_b16(bf16x8 a, bf16x8 b, f32x4 c){
  return __builtin_amdgcn_mfma_f32_16x16x32_bf16(a, b, c, 0, 0, 0);
}

// async global->LDS, 16B/lane; LDS dest is wave-uniform base + lane*16
typedef __attribute__((address_space(1))) const unsigned int* gas1p;
typedef __attribute__((address_space(3))) unsigned int* las3p;
__device__ __forceinline__ void gll16(const void* g, void* l){
  __builtin_amdgcn_global_load_lds((gas1p)g, (las3p)l, 16, 0, 0);
}

// pack weight [K x 128] f32 row-major -> MFMA B-fragment order (bf16); rows >= Klimit -> 0.
// perm=1: output tile (nb, ll) computes feature 2*((nb>>1)*16+ll) + (nb&1)
__global__ __launch_bounds__(256) void pack_b(const float* __restrict__ src,
    unsigned short* __restrict__ dst, int K, int Klimit, int srcLayerStride, int perm){
  int layer = blockIdx.y;
  int tid = blockIdx.x*256 + threadIdx.x;           // < K*128
  int j = tid & 7, lane = (tid >> 3) & 63, nb = (tid >> 9) & 7, kk = tid >> 12;
  int krow = (kk << 5) + ((lane >> 4) << 3) + j;
  int ll = lane & 15;
  int c = perm ? (((((nb >> 1) << 4) + ll) << 1) + (nb & 1)) : ((nb << 4) + ll);
  float v = (krow < Klimit) ? src[(size_t)layer*srcLayerStride + krow*HD + c] : 0.f;
  dst[(size_t)layer*K*HD + tid] = f2bf(v);
}

__global__ __launch_bounds__(256) void emb_kernel(
    const float* __restrict__ loc, const float* __restrict__ vel,
    const float* __restrict__ ew, const float* __restrict__ eb,
    float* __restrict__ hf, unsigned short* __restrict__ hb)
{
  int gid = blockIdx.x*256 + threadIdx.x;   // = n*128 + j
  int n = gid >> 7, j = gid & 127;
  float s = eb[j];
  s += loc[n*3+0]*ew[0*HD+j] + loc[n*3+1]*ew[1*HD+j] + loc[n*3+2]*ew[2*HD+j];
  s += vel[n*3+0]*ew[3*HD+j] + vel[n*3+1]*ew[4*HD+j] + vel[n*3+2]*ew[5*HD+j];
  hf[gid] = s;
  hb[gid] = f2bf(s);
}

// ---- CSR build (parallel 3-phase scan; only `cur` is consumed downstream) ----
__global__ __launch_bounds__(256) void count_kernel(const int* __restrict__ rowIdx, int* __restrict__ cnt){
  int e = blockIdx.x*256 + threadIdx.x;
  if (e < NE) atomicAdd(cnt + rowIdx[e], 1);
}

__global__ __launch_bounds__(256) void blocksum_kernel(const int* __restrict__ cnt, int* __restrict__ bsum){
  __shared__ int s[256];
  int t = threadIdx.x, i = blockIdx.x*256 + t;
  s[t] = (i < NN) ? cnt[i] : 0;
  __syncthreads();
  for (int d = 128; d > 0; d >>= 1){
    if (t < d) s[t] += s[t + d];
    __syncthreads();
  }
  if (t == 0) bsum[blockIdx.x] = s[0];
}

__global__ __launch_bounds__(256) void scanb_kernel(int* __restrict__ bsum){
  __shared__ int s[256];
  int t = threadIdx.x;
  int v = (t < NSCB) ? bsum[t] : 0;
  s[t] = v;
  __syncthreads();
  for (int d = 1; d < 256; d <<= 1){
    int u = (t >= d) ? s[t-d] : 0;
    __syncthreads();
    s[t] += u;
    __syncthreads();
  }
  if (t < NSCB) bsum[t] = s[t] - v;   // exclusive
}

__global__ __launch_bounds__(256) void offsets_kernel(const int* __restrict__ cnt,
    const int* __restrict__ bsum, int* __restrict__ cur){
  __shared__ int s[256];
  int t = threadIdx.x, i = blockIdx.x*256 + t;
  int v = (i < NN) ? cnt[i] : 0;
  s[t] = v;
  __syncthreads();
  for (int d = 1; d < 256; d <<= 1){
    int u = (t >= d) ? s[t-d] : 0;
    __syncthreads();
    s[t] += u;
    __syncthreads();
  }
  if (i < NN) cur[i] = bsum[blockIdx.x] + s[t] - v;
}

// row-sorted edges, permuted within each 64-block so an MFMA lane's 16 (r,i) edges are
// contiguous in sorted order -> long same-node runs for the fused scatter.
__global__ __launch_bounds__(256) void assign_kernel(
    const int* __restrict__ rowIdx, const int* __restrict__ colIdx,
    const float* __restrict__ ea, int* __restrict__ cur,
    int* __restrict__ row_s, int* __restrict__ col_s, float* __restrict__ ea_s){
  int e = blockIdx.x*256 + threadIdx.x;
  if (e < NE){
    int r = rowIdx[e];
    int s = atomicAdd(cur + r, 1);
    int s64 = s & 63;
    int sp = (s & ~63) | (((s64 >> 2) & 3) << 4) | (((s64 >> 4) & 3) << 2) | (s64 & 3);
    row_s[sp] = r;
    col_s[sp] = colIdx[e];
    ea_s[2*sp]   = ea[2*e];
    ea_s[2*sp+1] = ea[2*e+1];
  }
}

// swizzle for ep1 output / GEMM2 A reads: byte bits [5:4] ^= bits [9:8]
#define SWZ(a) ((a) ^ (((a) >> 4) & 0x30))

// ---- edge kernel: two-tile persistent pipeline; gll staging only (no reg staging),
//      16KB K-split, rank-2 ea epilogue, pk-bf16 fused atomic agg, XCD swizzle ----
__global__ __launch_bounds__(256, 8) void edge_kernel(
    const unsigned short* __restrict__ hb,
    const int* __restrict__ row_s, const int* __restrict__ col_s,
    const float* __restrict__ ea_s,
    const unsigned short* __restrict__ B1p, const unsigned short* __restrict__ B2p,
    const float* __restrict__ bias1, const float* __restrict__ bias2,
    const float* __restrict__ wea,      // [0..127]=row256 (ea0), [128..255]=row257 (ea1)
    unsigned short* __restrict__ aggb)
{
  __shared__ alignas(128) char sA[1024*16];   // 16 KB: 4 kk-blocks of frag slots
  __shared__ int sRow[2][64];
  __shared__ float2 sEa[2][64];
  uint4* sA4 = reinterpret_cast<uint4*>(sA);

  const int t = threadIdx.x;
  const int w = t >> 6, l = t & 63, lw = l >> 4, ll = l & 15;

  // XCD swizzle: 4688 = 8*586 exactly -> bijective chunked remap
  const int orig = blockIdx.x;
  const int bid = (orig & 7)*586 + (orig >> 3);
  const int tile0 = bid << 1;

  { // prologue: stage row(tile0) + sRow/sEa[0]
    const int e0 = tile0 << 6;
    if (t < 64){
      sRow[0][t] = row_s[e0 + t];
      sEa[0][t] = reinterpret_cast<const float2*>(ea_s)[e0 + t];
    }
    const int er = e0 + (w << 4) + ll;
    const unsigned short* gr = hb + (size_t)row_s[er]*HD + (lw << 3);
    #pragma unroll
    for (int kk = 0; kk < 4; ++kk)
      gll16(gr + (kk << 5), sA + ((size_t)(((kk << 2) + w)) << 10));
    asm volatile("s_waitcnt vmcnt(0)" ::: "memory");
  }
  __syncthreads();

  const int q2 = ((w << 4) + ll) << 1;
  const float2 bb1 = *reinterpret_cast<const float2*>(bias1 + q2);
  const float2 wA = *reinterpret_cast<const float2*>(wea + q2);        // row256 pair
  const float2 wB = *reinterpret_cast<const float2*>(wea + HD + q2);   // row257 pair
  const float2 bb2 = *reinterpret_cast<const float2*>(bias2 + q2);

  #pragma unroll
  for (int hh = 0; hh < 2; ++hh){
    const int tile = tile0 + hh;
    const int erh = (tile << 6) + (w << 4) + ll;

    f32x4 acc[4][2] = {};
    #pragma unroll
    for (int kk = 0; kk < 4; ++kk){
      bf16x8 a[4], b[2];
      #pragma unroll
      for (int r = 0; r < 4; ++r)
        a[r] = *reinterpret_cast<const bf16x8*>(&sA4[((kk << 2) + r)*64 + l]);
      #pragma unroll
      for (int c = 0; c < 2; ++c)
        b[c] = *reinterpret_cast<const bf16x8*>(B1p + ((((kk << 3) + (w << 1) + c) << 6) + l)*8);
      #pragma unroll
      for (int r = 0; r < 4; ++r)
        #pragma unroll
        for (int c = 0; c < 2; ++c)
          acc[r][c] = mfma_b16(a[r], b[c], acc[r][c]);
    }
    __syncthreads();   // half1 reads done

    { // stage col half (gll only)
      const unsigned short* gc = hb + (size_t)col_s[erh]*HD + (lw << 3);
      #pragma unroll
      for (int kk = 0; kk < 4; ++kk)
        gll16(gc + (kk << 5), sA + ((size_t)(((kk << 2) + w)) << 10));
      asm volatile("s_waitcnt vmcnt(0)" ::: "memory");
    }
    __syncthreads();

    #pragma unroll
    for (int kk = 4; kk < 8; ++kk){
      bf16x8 a[4], b[2];
      #pragma unroll
      for (int r = 0; r < 4; ++r)
        a[r] = *reinterpret_cast<const bf16x8*>(&sA4[(((kk - 4) << 2) + r)*64 + l]);
      #pragma unroll
      for (int c = 0; c < 2; ++c)
        b[c] = *reinterpret_cast<const bf16x8*>(B1p + ((((kk << 3) + (w << 1) + c) << 6) + l)*8);
      #pragma unroll
      for (int r = 0; r < 4; ++r)
        #pragma unroll
        for (int c = 0; c < 2; ++c)
          acc[r][c] = mfma_b16(a[r], b[c], acc[r][c]);
    }
    __syncthreads();   // half2 reads done before ep1 overwrites

    // ep1 (paired outputs): + bias + ea rank-2 + SiLU -> pk -> swizzled dword write
    #pragma unroll
    for (int r = 0; r < 4; ++r){
      #pragma unroll
      for (int i = 0; i < 4; ++i){
        int rt = (r << 4) + (lw << 2) + i;
        float2 eav = sEa[hh][rt];
        float v0 = silu_f(acc[r][0][i] + bb1.x + eav.x*wA.x + eav.y*wB.x);
        float v1 = silu_f(acc[r][1][i] + bb1.y + eav.x*wA.y + eav.y*wB.y);
        unsigned d = pk_bf16(v0, v1);
        int a0 = ((((w << 2) + r) << 10) | ((ll >> 2) << 8) | (lw << 6) | (i << 4) | ((ll & 3) << 2));
        *reinterpret_cast<unsigned*>(sA + SWZ(a0)) = d;
      }
    }
    __syncthreads();

    f32x4 acc2[4][2] = {};
    #pragma unroll
    for (int kk = 0; kk < 4; ++kk){
      bf16x8 a[4], b[2];
      #pragma unroll
      for (int r = 0; r < 4; ++r){
        int a0 = ((((kk << 2) + r) << 10) | (l << 4));
        a[r] = *reinterpret_cast<const bf16x8*>(sA + SWZ(a0));
      }
      #pragma unroll
      for (int c = 0; c < 2; ++c)
        b[c] = *reinterpret_cast<const bf16x8*>(B2p + ((((kk << 3) + (w << 1) + c) << 6) + l)*8);
      #pragma unroll
      for (int r = 0; r < 4; ++r)
        #pragma unroll
        for (int c = 0; c < 2; ++c)
          acc2[r][c] = mfma_b16(a[r], b[c], acc2[r][c]);
    }
    __syncthreads();   // GEMM2 LDS reads done -> kk0-3 region is free

    const bool more = (hh == 0) && (tile0 + 1 < NTILE);
    if (more){
      // prefetch tile1's row half into LDS (async) + sRow/sEa[1]; overlaps ep2 below
      const int e1 = (tile0 + 1) << 6;
      if (t < 64){
        sRow[1][t] = row_s[e1 + t];
        sEa[1][t] = reinterpret_cast<const float2*>(ea_s)[e1 + t];
      }
      const int er1 = e1 + (w << 4) + ll;
      const unsigned short* gr1 = hb + (size_t)row_s[er1]*HD + (lw << 3);
      #pragma unroll
      for (int kk = 0; kk < 4; ++kk)
        gll16(gr1 + (kk << 5), sA + ((size_t)(((kk << 2) + w)) << 10));
    }

    // ep2 (B2p perm=1 -> adjacent features 2q,2q+1): run-merged, ONE pk-bf16 atomic/flush
    {
      int curNode = -1;
      float s0 = 0.f, s1 = 0.f;
      #pragma unroll
      for (int r = 0; r < 4; ++r){
        #pragma unroll
        for (int i = 0; i < 4; ++i){
          int rt = (r << 4) + (lw << 2) + i;
          int nd = sRow[hh][rt];
          float v0 = silu_f(acc2[r][0][i] + bb2.x);
          float v1 = silu_f(acc2[r][1][i] + bb2.y);
          if (nd != curNode){
            if (curNode >= 0)
              atomic_pk_add_bf16(aggb + (size_t)curNode*HD + q2, pk_bf16(s0, s1));
            curNode = nd; s0 = v0; s1 = v1;
          } else { s0 += v0; s1 += v1; }
        }
      }
      atomic_pk_add_bf16(aggb + (size_t)curNode*HD + q2, pk_bf16(s0, s1));
    }

    if (hh == 0){
      if (!more) return;   // last (odd) tile: block is done
      asm volatile("s_waitcnt vmcnt(0)" ::: "memory");   // tile1 row staged
      __syncthreads();
    }
  }
}

// ---- node kernel (exact R10): gll staging (h then aggb) + aggb self-zeroing ----
__global__ __launch_bounds__(256, 8) void node_kernel(
    unsigned short* hb, unsigned short* aggb,
    const unsigned short* __restrict__ B1p, const unsigned short* __restrict__ B2p,
    const float* __restrict__ bias1, const float* __restrict__ bias2,
    float* hf)
{
  __shared__ alignas(128) char sA[1024*16];
  uint4* sA4 = reinterpret_cast<uint4*>(sA);
  const int t = threadIdx.x;
  const int w = t >> 6, l = t & 63, lw = l >> 4, ll = l & 15;
  const int n0 = blockIdx.x << 6;

  const int nlane = n0 + (w << 4) + ll;
  const int ncl = (nlane < NN) ? nlane : 0;
  const unsigned short* gh = hb + (size_t)ncl*HD + (lw << 3);
  #pragma unroll
  for (int kk = 0; kk < 4; ++kk)
    gll16(gh + (kk << 5), sA + ((size_t)(((kk << 2) + w)) << 10));
  asm volatile("s_waitcnt vmcnt(0)" ::: "memory");
  __syncthreads();

  const int q2 = ((w << 4) + ll) << 1;
  const float2 bb1 = *reinterpret_cast<const float2*>(bias1 + q2);

  f32x4 acc[4][2] = {};
  #pragma unroll
  for (int kk = 0; kk < 4; ++kk){
    bf16x8 a[4], b[2];
    #pragma unroll
    for (int r = 0; r < 4; ++r)
      a[r] = *reinterpret_cast<const bf16x8*>(&sA4[((kk << 2) + r)*64 + l]);
    #pragma unroll
    for (int c = 0; c < 2; ++c)
      b[c] = *reinterpret_cast<const bf16x8*>(B1p + ((((kk << 3) + (w << 1) + c) << 6) + l)*8);
    #pragma unroll
    for (int r = 0; r < 4; ++r)
      #pragma unroll
      for (int c = 0; c < 2; ++c)
        acc[r][c] = mfma_b16(a[r], b[c], acc[r][c]);
  }
  __syncthreads();

  // stage agg half directly from bf16 aggb; then zero it for the next layer
  unsigned short* ga = aggb + (size_t)ncl*HD + (lw << 3);
  #pragma unroll
  for (int kk = 0; kk < 4; ++kk)
    gll16(ga + (kk << 5), sA + ((size_t)(((kk << 2) + w)) << 10));
  asm volatile("s_waitcnt vmcnt(0)" ::: "memory");
  if (nlane < NN){
    const uint4 z4 = make_uint4(0u, 0u, 0u, 0u);
    #pragma unroll
    for (int kk = 0; kk < 4; ++kk)
      *reinterpret_cast<uint4*>(ga + (kk << 5)) = z4;
  }
  __syncthreads();

  #pragma unroll
  for (int kk = 4; kk < 8; ++kk){
    bf16x8 a[4], b[2];
    #pragma unroll
    for (int r = 0; r < 4; ++r)
      a[r] = *reinterpret_cast<const bf16x8*>(&sA4[(((kk - 4) << 2) + r)*64 + l]);
    #pragma unroll
    for (int c = 0; c < 2; ++c)
      b[c] = *reinterpret_cast<const bf16x8*>(B1p + ((((kk << 3) + (w << 1) + c) << 6) + l)*8);
    #pragma unroll
    for (int r = 0; r < 4; ++r)
      #pragma unroll
      for (int c = 0; c < 2; ++c)
        acc[r][c] = mfma_b16(a[r], b[c], acc[r][c]);
  }
  __syncthreads();

  #pragma unroll
  for (int r = 0; r < 4; ++r){
    #pragma unroll
    for (int i = 0; i < 4; ++i){
      unsigned d = pk_bf16(silu_f(acc[r][0][i] + bb1.x), silu_f(acc[r][1][i] + bb1.y));
      int a0 = ((((w << 2) + r) << 10) | ((ll >> 2) << 8) | (lw << 6) | (i << 4) | ((ll & 3) << 2));
      *reinterpret_cast<unsigned*>(sA + SWZ(a0)) = d;
    }
  }
  __syncthreads();

  f32x4 acc2[4][2] = {};
  #pragma unroll
  for (int kk = 0; kk < 4; ++kk){
    bf16x8 a[4], b[2];
    #pragma unroll
    for (int r = 0; r < 4; ++r){
      int a0 = ((((kk << 2) + r) << 10) | (l << 4));
      a[r] = *reinterpret_cast<const bf16x8*>(sA + SWZ(a0));
    }
    #pragma unroll
    for (int c = 0; c < 2; ++c)
      b[c] = *reinterpret_cast<const bf16x8*>(B2p + ((((kk << 3) + (w << 1) + c) << 6) + l)*8);
    #pragma unroll
    for (int r = 0; r < 4; ++r)
      #pragma unroll
      for (int c = 0; c < 2; ++c)
        acc2[r][c] = mfma_b16(a[r], b[c], acc2[r][c]);
  }

  // final epilogue (paired): residual f32 + bf16 mirror
  {
    const float2 bb2 = *reinterpret_cast<const float2*>(bias2 + q2);
    #pragma unroll
    for (int r = 0; r < 4; ++r){
      #pragma unroll
      for (int i = 0; i < 4; ++i){
        int rt = (r << 4) + (lw << 2) + i;
        int n = n0 + rt;
        if (n < NN){
          float2 ho = *reinterpret_cast<const float2*>(hf + (size_t)n*HD + q2);
          float h0 = ho.x + acc2[r][0][i] + bb2.x;
          float h1 = ho.y + acc2[r][1][i] + bb2.y;
          *reinterpret_cast<float2*>(hf + (size_t)n*HD + q2) = make_float2(h0, h1);
          *reinterpret_cast<unsigned*>(hb + (size_t)n*HD + q2) = pk_bf16(h0, h1);
        }
      }
    }
  }
}

// ---- decoder: out = silu(h @ dw1 + db1) @ dw2 + db2 ----
__global__ __launch_bounds__(256) void dec_kernel(
    const unsigned short* __restrict__ hb, const unsigned short* __restrict__ D1p,
    const float* __restrict__ db1, const float* __restrict__ dw2,
    const float* __restrict__ db2, float* __restrict__ outp)
{
  __shared__ alignas(128) char sA[1024*16];
  uint4* sA4 = reinterpret_cast<uint4*>(sA);
  __shared__ float sT[64*133];
  const int t = threadIdx.x;
  const int n0 = blockIdx.x << 6;
  {
    const int nl_ = t >> 2, p = t & 3;
    const int n = n0 + nl_;
    const bool valid = (n < NN);
    const int nc = valid ? n : 0;
    const uint4* src = reinterpret_cast<const uint4*>(hb + (size_t)nc*HD);
    const int base16 = ((nl_ >> 4) << 6) + (nl_ & 15);
    #pragma unroll
    for (int c = 0; c < 4; ++c){
      int q = (p << 2) + c;
      uint4 d = valid ? src[q] : make_uint4(0,0,0,0);
      sA4[base16 + ((q >> 2) << 8) + ((q & 3) << 4)] = d;
    }
  }
  __syncthreads();

  const int w = t >> 6, l = t & 63;
  const int lw = l >> 4, ll = l & 15;

  f32x4 acc[4][2] = {};
  #pragma unroll
  for (int kk = 0; kk < 4; ++kk){
    bf16x8 a[4], b[2];
    #pragma unroll
    for (int r = 0; r < 4; ++r)
      a[r] = *reinterpret_cast<const bf16x8*>(&sA4[((kk << 2) + r)*64 + l]);
    #pragma unroll
    for (int c = 0; c < 2; ++c)
      b[c] = *reinterpret_cast<const bf16x8*>(D1p + ((((kk << 3) + (w << 1) + c) << 6) + l)*8);
    #pragma unroll
    for (int r = 0; r < 4; ++r)
      #pragma unroll
      for (int c = 0; c < 2; ++c)
        acc[r][c] = mfma_b16(a[r], b[c], acc[r][c]);
  }
  #pragma unroll
  for (int r = 0; r < 4; ++r){
    #pragma unroll
    for (int i = 0; i < 4; ++i){
      int rt = (r << 4) + (lw << 2) + i;
      #pragma unroll
      for (int c = 0; c < 2; ++c){
        int col = (w << 5) + (c << 4) + ll;
        sT[rt*133 + col] = silu_f(acc[r][c][i] + db1[col]);
      }
    }
  }
  __syncthreads();
  if (t < 192){
    int rr = t & 63, cc = t >> 6;
    int n = n0 + rr;
    if (n < NN){
      float s = db2[cc];
      #pragma unroll 8
      for (int k = 0; k < HD; ++k) s += sT[rr*133 + k]*dw2[k*3 + cc];
      outp[(size_t)n*3 + cc] = s;
    }
  }
}

static inline char* alignup(char* p, size_t a){ return (char*)(((uintptr_t)p + a - 1) & ~(a - 1)); }

extern "C" void kernel_launch(void* const* d_in, const int* in_sizes, int n_in,
                              void* d_out, int out_size, void* d_ws, size_t ws_size,
                              hipStream_t stream)
{
  const float* loc  = (const float*)d_in[0];
  const float* vel  = (const float*)d_in[1];
  const float* ea   = (const float*)d_in[2];
  const int*   row  = (const int*)d_in[3];
  const int*   col  = (const int*)d_in[4];
  const float* embw = (const float*)d_in[5];
  const float* embb = (const float*)d_in[6];
  const float* ew1  = (const float*)d_in[7];
  const float* eb1  = (const float*)d_in[8];
  const float* ew2  = (const float*)d_in[9];
  const float* eb2  = (const float*)d_in[10];
  const float* nw1  = (const float*)d_in[11];
  const float* nb1  = (const float*)d_in[12];
  const float* nw2  = (const float*)d_in[13];
  const float* nb2  = (const float*)d_in[14];
  const float* dw1  = (const float*)d_in[15];
  const float* db1  = (const float*)d_in[16];
  const float* dw2  = (const float*)d_in[17];
  const float* db2  = (const float*)d_in[18];

  char* p = (char*)d_ws;
  float* hf = (float*)p;                       p += (size_t)NN*HD*4;
  unsigned short* hbuf = (unsigned short*)p;   p += (size_t)NN*HD*2;
  unsigned short* aggb = (unsigned short*)p;   p += (size_t)NN*HD*2;
  int* cnt = (int*)p;                          p += (size_t)NN*4;
  int* cur = (int*)p;                          p += (size_t)NN*4;
  int* bsum = (int*)p;                         p += (size_t)256*4;   p = alignup(p, 256);
  int* row_s = (int*)p;                        p += (size_t)NE*4;
  int* col_s = (int*)p;                        p += (size_t)NE*4;
  float* ea_s = (float*)p;                     p += (size_t)NE*2*4;
  unsigned short* ew1p = (unsigned short*)p;   p += (size_t)NL*256*HD*2;
  unsigned short* ew2p = (unsigned short*)p;   p += (size_t)NL*128*HD*2;
  unsigned short* nw1p = (unsigned short*)p;   p += (size_t)NL*256*HD*2;
  unsigned short* nw2p = (unsigned short*)p;   p += (size_t)NL*128*HD*2;
  unsigned short* dw1p = (unsigned short*)p;   p += (size_t)128*HD*2;

  // CSR build (parallel scan; once per launch)
  hipMemsetAsync(cnt, 0, (size_t)NN*4, stream);
  count_kernel<<<(NE + 255)/256, 256, 0, stream>>>(row, cnt);
  blocksum_kernel<<<NSCB, 256, 0, stream>>>(cnt, bsum);
  scanb_kernel<<<1, 256, 0, stream>>>(bsum);
  offsets_kernel<<<NSCB, 256, 0, stream>>>(cnt, bsum, cur);
  assign_kernel<<<(NE + 255)/256, 256, 0, stream>>>(row, col, ea, cur, row_s, col_s, ea_s);

  pack_b<<<dim3(128, NL), 256, 0, stream>>>(ew1, ew1p, 256, 256, 258*HD, 1);  // ea rows via epilogue
  pack_b<<<dim3(64,  NL), 256, 0, stream>>>(ew2, ew2p, 128, 128, 128*HD, 1);  // paired -> pk atomics
  pack_b<<<dim3(128, NL), 256, 0, stream>>>(nw1, nw1p, 256, 256, 256*HD, 1);
  pack_b<<<dim3(64,  NL), 256, 0, stream>>>(nw2, nw2p, 128, 128, 128*HD, 1);
  pack_b<<<dim3(64,  1 ), 256, 0, stream>>>(dw1, dw1p, 128, 128, 0, 0);

  emb_kernel<<<(NN*HD)/256, 256, 0, stream>>>(loc, vel, embw, embb, hf, hbuf);

  hipMemsetAsync(aggb, 0, (size_t)NN*HD*2, stream);   // layer 0; later layers zeroed by node_kernel
  for (int i = 0; i < NL; ++i){
    edge_kernel<<<NWG_E2, 256, 0, stream>>>(hbuf, row_s, col_s, ea_s,
        ew1p + (size_t)i*256*HD, ew2p + (size_t)i*128*HD,
        eb1 + i*HD, eb2 + i*HD,
        ew1 + (size_t)i*258*HD + 256*HD, aggb);
    node_kernel<<<(NN + 63)/64, 256, 0, stream>>>(hbuf, aggb,
        nw1p + (size_t)i*256*HD, nw2p + (size_t)i*128*HD,
        nb1 + i*HD, nb2 + i*HD, hf);
  }

  dec_kernel<<<(NN + 63)/64, 256, 0, stream>>>(hbuf, dw1p, db1, dw2, db2, (float*)d_out);
}

// Round 14
// 586.070 us; speedup vs baseline: 1.4827x; 1.4827x over previous
//
#include <hip/hip_runtime.h>

#define NN 50000
#define NE 600000
#define HD 128
#define NL 4
#define NSCB 196   // ceil(NN/256)
#define NWG_E (NE/64)   // 9375 edge blocks

typedef __bf16 bf16x8 __attribute__((ext_vector_type(8)));
typedef float f32x4 __attribute__((ext_vector_type(4)));

__device__ __forceinline__ unsigned short f2bf(float x){
  union { float f; unsigned int u; } v; v.f = x;
  unsigned int r = v.u + 0x7FFFu + ((v.u >> 16) & 1u);
  return (unsigned short)(r >> 16);
}
// silu via raw trans ops: avoids precise-div expansion
__device__ __forceinline__ float silu_f(float x){
  float e, r;
  float t = x * -1.44269504088896340736f;
  asm("v_exp_f32 %0, %1" : "=v"(e) : "v"(t));
  float d = 1.f + e;
  asm("v_rcp_f32 %0, %1" : "=v"(r) : "v"(d));
  return x * r;
}
__device__ __forceinline__ unsigned pk_bf16(float v0, float v1){
  unsigned r;
  asm("v_cvt_pk_bf16_f32 %0, %1, %2" : "=v"(r) : "v"(v0), "v"(v1));
  return r;
}
// packed bf16x2 atomic add (gfx950 GLOBAL_ATOMIC_PK_ADD_BF16), no return
__device__ __forceinline__ void atomic_pk_add_bf16(unsigned short* addr, unsigned data){
  asm volatile("global_atomic_pk_add_bf16 %0, %1, off"
    :: "v"((unsigned long long)(uintptr_t)addr), "v"(data) : "memory");
}

__device__ __forceinline__ f32x4 mfma_b16(bf16x8 a, bf16x8 b, f32x4 c){
  return __builtin_amdgcn_mfma_f32_16x16x32_bf16(a, b, c, 0, 0, 0);
}

// async global->LDS, 16B/lane; LDS dest is wave-uniform base + lane*16
typedef __attribute__((address_space(1))) const unsigned int* gas1p;
typedef __attribute__((address_space(3))) unsigned int* las3p;
__device__ __forceinline__ void gll16(const void* g, void* l){
  __builtin_amdgcn_global_load_lds((gas1p)g, (las3p)l, 16, 0, 0);
}

// pack weight [K x 128] f32 row-major -> MFMA B-fragment order (bf16); rows >= Klimit -> 0.
// perm=1: output tile (nb, ll) computes feature 2*((nb>>1)*16+ll) + (nb&1)
__global__ __launch_bounds__(256) void pack_b(const float* __restrict__ src,
    unsigned short* __restrict__ dst, int K, int Klimit, int srcLayerStride, int perm){
  int layer = blockIdx.y;
  int tid = blockIdx.x*256 + threadIdx.x;           // < K*128
  int j = tid & 7, lane = (tid >> 3) & 63, nb = (tid >> 9) & 7, kk = tid >> 12;
  int krow = (kk << 5) + ((lane >> 4) << 3) + j;
  int ll = lane & 15;
  int c = perm ? (((((nb >> 1) << 4) + ll) << 1) + (nb & 1)) : ((nb << 4) + ll);
  float v = (krow < Klimit) ? src[(size_t)layer*srcLayerStride + krow*HD + c] : 0.f;
  dst[(size_t)layer*K*HD + tid] = f2bf(v);
}

__global__ __launch_bounds__(256) void emb_kernel(
    const float* __restrict__ loc, const float* __restrict__ vel,
    const float* __restrict__ ew, const float* __restrict__ eb,
    float* __restrict__ hf, unsigned short* __restrict__ hb)
{
  int gid = blockIdx.x*256 + threadIdx.x;   // = n*128 + j
  int n = gid >> 7, j = gid & 127;
  float s = eb[j];
  s += loc[n*3+0]*ew[0*HD+j] + loc[n*3+1]*ew[1*HD+j] + loc[n*3+2]*ew[2*HD+j];
  s += vel[n*3+0]*ew[3*HD+j] + vel[n*3+1]*ew[4*HD+j] + vel[n*3+2]*ew[5*HD+j];
  hf[gid] = s;
  hb[gid] = f2bf(s);
}

// ---- CSR build (parallel 3-phase scan; only `cur` is consumed downstream) ----
__global__ __launch_bounds__(256) void count_kernel(const int* __restrict__ rowIdx, int* __restrict__ cnt){
  int e = blockIdx.x*256 + threadIdx.x;
  if (e < NE) atomicAdd(cnt + rowIdx[e], 1);
}

__global__ __launch_bounds__(256) void blocksum_kernel(const int* __restrict__ cnt, int* __restrict__ bsum){
  __shared__ int s[256];
  int t = threadIdx.x, i = blockIdx.x*256 + t;
  s[t] = (i < NN) ? cnt[i] : 0;
  __syncthreads();
  for (int d = 128; d > 0; d >>= 1){
    if (t < d) s[t] += s[t + d];
    __syncthreads();
  }
  if (t == 0) bsum[blockIdx.x] = s[0];
}

__global__ __launch_bounds__(256) void scanb_kernel(int* __restrict__ bsum){
  __shared__ int s[256];
  int t = threadIdx.x;
  int v = (t < NSCB) ? bsum[t] : 0;
  s[t] = v;
  __syncthreads();
  for (int d = 1; d < 256; d <<= 1){
    int u = (t >= d) ? s[t-d] : 0;
    __syncthreads();
    s[t] += u;
    __syncthreads();
  }
  if (t < NSCB) bsum[t] = s[t] - v;   // exclusive
}

__global__ __launch_bounds__(256) void offsets_kernel(const int* __restrict__ cnt,
    const int* __restrict__ bsum, int* __restrict__ cur){
  __shared__ int s[256];
  int t = threadIdx.x, i = blockIdx.x*256 + t;
  int v = (i < NN) ? cnt[i] : 0;
  s[t] = v;
  __syncthreads();
  for (int d = 1; d < 256; d <<= 1){
    int u = (t >= d) ? s[t-d] : 0;
    __syncthreads();
    s[t] += u;
    __syncthreads();
  }
  if (i < NN) cur[i] = bsum[blockIdx.x] + s[t] - v;
}

// row-sorted edges, permuted within each 64-block so an MFMA lane's 16 (r,i) edges are
// contiguous in sorted order -> long same-node runs for the fused scatter.
__global__ __launch_bounds__(256) void assign_kernel(
    const int* __restrict__ rowIdx, const int* __restrict__ colIdx,
    const float* __restrict__ ea, int* __restrict__ cur,
    int* __restrict__ row_s, int* __restrict__ col_s, float* __restrict__ ea_s){
  int e = blockIdx.x*256 + threadIdx.x;
  if (e < NE){
    int r = rowIdx[e];
    int s = atomicAdd(cur + r, 1);
    int s64 = s & 63;
    int sp = (s & ~63) | (((s64 >> 2) & 3) << 4) | (((s64 >> 4) & 3) << 2) | (s64 & 3);
    row_s[sp] = r;
    col_s[sp] = colIdx[e];
    ea_s[2*sp]   = ea[2*e];
    ea_s[2*sp+1] = ea[2*e+1];
  }
}

// swizzle for ep1 output / GEMM2 A reads: byte bits [5:4] ^= bits [9:8]
#define SWZ(a) ((a) ^ (((a) >> 4) & 0x30))

// ---- edge kernel: gll staging, 16KB K-split, rank-2 ea epilogue, pk-bf16 fused atomic agg,
//      XCD-bijective block swizzle so each XCD's atomics cover a contiguous ~3 MB agg range ----
__global__ __launch_bounds__(256, 8) void edge_kernel(
    const unsigned short* __restrict__ hb,
    const int* __restrict__ row_s, const int* __restrict__ col_s,
    const float* __restrict__ ea_s,
    const unsigned short* __restrict__ B1p, const unsigned short* __restrict__ B2p,
    const float* __restrict__ bias1, const float* __restrict__ bias2,
    const float* __restrict__ wea,      // [0..127]=row256 (ea0), [128..255]=row257 (ea1)
    unsigned short* __restrict__ aggb)
{
  __shared__ alignas(128) char sA[1024*16];   // 16 KB: 4 kk-blocks of frag slots
  __shared__ int sRow[64];
  __shared__ float2 sEa[64];
  uint4* sA4 = reinterpret_cast<uint4*>(sA);

  const int t = threadIdx.x;
  const int w = t >> 6, l = t & 63, lw = l >> 4, ll = l & 15;

  // bijective XCD swizzle (nwg = 9375 = 8*1171 + 7)
  int orig = blockIdx.x;
  int xcd = orig & 7, idx = orig >> 3;
  const int qq = NWG_E >> 3, rr = NWG_E & 7;   // 1171, 7
  int bid = (xcd < rr) ? xcd*(qq + 1) + idx : rr*(qq + 1) + (xcd - rr)*qq + idx;
  const int e0 = bid << 6;

  if (t < 64){
    sRow[t] = row_s[e0 + t];
    sEa[t] = reinterpret_cast<const float2*>(ea_s)[e0 + t];
  }
  // wave w stages r-tile w; lane l -> edge w*16+(l&15), k-chunk (l>>4)
  const int er = e0 + (w << 4) + ll;
  const int nrow = row_s[er];
  const int ncol = col_s[er];
  const unsigned short* gr = hb + (size_t)nrow*HD + (lw << 3);
  #pragma unroll
  for (int kk = 0; kk < 4; ++kk)
    gll16(gr + (kk << 5), sA + ((size_t)(((kk << 2) + w)) << 10));
  asm volatile("s_waitcnt vmcnt(0)" ::: "memory");
  __syncthreads();

  const int q2 = ((w << 4) + ll) << 1;
  const float2 bb1 = *reinterpret_cast<const float2*>(bias1 + q2);
  const float2 wA = *reinterpret_cast<const float2*>(wea + q2);        // row256 pair
  const float2 wB = *reinterpret_cast<const float2*>(wea + HD + q2);   // row257 pair

  f32x4 acc[4][2] = {};
  #pragma unroll
  for (int kk = 0; kk < 4; ++kk){
    bf16x8 a[4], b[2];
    #pragma unroll
    for (int r = 0; r < 4; ++r)
      a[r] = *reinterpret_cast<const bf16x8*>(&sA4[((kk << 2) + r)*64 + l]);
    #pragma unroll
    for (int c = 0; c < 2; ++c)
      b[c] = *reinterpret_cast<const bf16x8*>(B1p + ((((kk << 3) + (w << 1) + c) << 6) + l)*8);
    #pragma unroll
    for (int r = 0; r < 4; ++r)
      #pragma unroll
      for (int c = 0; c < 2; ++c)
        acc[r][c] = mfma_b16(a[r], b[c], acc[r][c]);
  }
  __syncthreads();   // all half1 reads done

  const unsigned short* gc = hb + (size_t)ncol*HD + (lw << 3);
  #pragma unroll
  for (int kk = 0; kk < 4; ++kk)
    gll16(gc + (kk << 5), sA + ((size_t)(((kk << 2) + w)) << 10));
  asm volatile("s_waitcnt vmcnt(0)" ::: "memory");
  __syncthreads();

  #pragma unroll
  for (int kk = 4; kk < 8; ++kk){
    bf16x8 a[4], b[2];
    #pragma unroll
    for (int r = 0; r < 4; ++r)
      a[r] = *reinterpret_cast<const bf16x8*>(&sA4[(((kk - 4) << 2) + r)*64 + l]);
    #pragma unroll
    for (int c = 0; c < 2; ++c)
      b[c] = *reinterpret_cast<const bf16x8*>(B1p + ((((kk << 3) + (w << 1) + c) << 6) + l)*8);
    #pragma unroll
    for (int r = 0; r < 4; ++r)
      #pragma unroll
      for (int c = 0; c < 2; ++c)
        acc[r][c] = mfma_b16(a[r], b[c], acc[r][c]);
  }
  __syncthreads();   // half2 reads done before ep1 overwrites

  // ep1 (paired outputs): + bias + ea rank-2 + SiLU -> pk -> swizzled dword write
  #pragma unroll
  for (int r = 0; r < 4; ++r){
    #pragma unroll
    for (int i = 0; i < 4; ++i){
      int rt = (r << 4) + (lw << 2) + i;
      float2 eav = sEa[rt];
      float v0 = silu_f(acc[r][0][i] + bb1.x + eav.x*wA.x + eav.y*wB.x);
      float v1 = silu_f(acc[r][1][i] + bb1.y + eav.x*wA.y + eav.y*wB.y);
      unsigned d = pk_bf16(v0, v1);
      int a0 = ((((w << 2) + r) << 10) | ((ll >> 2) << 8) | (lw << 6) | (i << 4) | ((ll & 3) << 2));
      *reinterpret_cast<unsigned*>(sA + SWZ(a0)) = d;
    }
  }
  __syncthreads();

  f32x4 acc2[4][2] = {};
  #pragma unroll
  for (int kk = 0; kk < 4; ++kk){
    bf16x8 a[4], b[2];
    #pragma unroll
    for (int r = 0; r < 4; ++r){
      int a0 = ((((kk << 2) + r) << 10) | (l << 4));
      a[r] = *reinterpret_cast<const bf16x8*>(sA + SWZ(a0));
    }
    #pragma unroll
    for (int c = 0; c < 2; ++c)
      b[c] = *reinterpret_cast<const bf16x8*>(B2p + ((((kk << 3) + (w << 1) + c) << 6) + l)*8);
    #pragma unroll
    for (int r = 0; r < 4; ++r)
      #pragma unroll
      for (int c = 0; c < 2; ++c)
        acc2[r][c] = mfma_b16(a[r], b[c], acc2[r][c]);
  }

  // ep2 (B2p perm=1 -> adjacent features 2q,2q+1): run-merged, ONE pk-bf16 atomic per flush
  {
    const float2 bb2 = *reinterpret_cast<const float2*>(bias2 + q2);
    int curNode = -1;
    float s0 = 0.f, s1 = 0.f;
    #pragma unroll
    for (int r = 0; r < 4; ++r){
      #pragma unroll
      for (int i = 0; i < 4; ++i){
        int rt = (r << 4) + (lw << 2) + i;
        int nd = sRow[rt];
        float v0 = silu_f(acc2[r][0][i] + bb2.x);
        float v1 = silu_f(acc2[r][1][i] + bb2.y);
        if (nd != curNode){
          if (curNode >= 0)
            atomic_pk_add_bf16(aggb + (size_t)curNode*HD + q2, pk_bf16(s0, s1));
          curNode = nd; s0 = v0; s1 = v1;
        } else { s0 += v0; s1 += v1; }
      }
    }
    atomic_pk_add_bf16(aggb + (size_t)curNode*HD + q2, pk_bf16(s0, s1));
  }
}

// ---- node kernel: gll staging (h then aggb) + aggb self-zeroing, 16KB K-split ----
__global__ __launch_bounds__(256, 8) void node_kernel(
    unsigned short* hb, unsigned short* aggb,
    const unsigned short* __restrict__ B1p, const unsigned short* __restrict__ B2p,
    const float* __restrict__ bias1, const float* __restrict__ bias2,
    float* hf)
{
  __shared__ alignas(128) char sA[1024*16];
  uint4* sA4 = reinterpret_cast<uint4*>(sA);
  const int t = threadIdx.x;
  const int w = t >> 6, l = t & 63, lw = l >> 4, ll = l & 15;
  const int n0 = blockIdx.x << 6;

  const int nlane = n0 + (w << 4) + ll;
  const int ncl = (nlane < NN) ? nlane : 0;
  const unsigned short* gh = hb + (size_t)ncl*HD + (lw << 3);
  #pragma unroll
  for (int kk = 0; kk < 4; ++kk)
    gll16(gh + (kk << 5), sA + ((size_t)(((kk << 2) + w)) << 10));
  asm volatile("s_waitcnt vmcnt(0)" ::: "memory");
  __syncthreads();

  const int q2 = ((w << 4) + ll) << 1;
  const float2 bb1 = *reinterpret_cast<const float2*>(bias1 + q2);

  f32x4 acc[4][2] = {};
  #pragma unroll
  for (int kk = 0; kk < 4; ++kk){
    bf16x8 a[4], b[2];
    #pragma unroll
    for (int r = 0; r < 4; ++r)
      a[r] = *reinterpret_cast<const bf16x8*>(&sA4[((kk << 2) + r)*64 + l]);
    #pragma unroll
    for (int c = 0; c < 2; ++c)
      b[c] = *reinterpret_cast<const bf16x8*>(B1p + ((((kk << 3) + (w << 1) + c) << 6) + l)*8);
    #pragma unroll
    for (int r = 0; r < 4; ++r)
      #pragma unroll
      for (int c = 0; c < 2; ++c)
        acc[r][c] = mfma_b16(a[r], b[c], acc[r][c]);
  }
  __syncthreads();

  // stage agg half directly from bf16 aggb; then zero it for the next layer
  unsigned short* ga = aggb + (size_t)ncl*HD + (lw << 3);
  #pragma unroll
  for (int kk = 0; kk < 4; ++kk)
    gll16(ga + (kk << 5), sA + ((size_t)(((kk << 2) + w)) << 10));
  asm volatile("s_waitcnt vmcnt(0)" ::: "memory");
  if (nlane < NN){
    const uint4 z4 = make_uint4(0u, 0u, 0u, 0u);
    #pragma unroll
    for (int kk = 0; kk < 4; ++kk)
      *reinterpret_cast<uint4*>(ga + (kk << 5)) = z4;
  }
  __syncthreads();

  #pragma unroll
  for (int kk = 4; kk < 8; ++kk){
    bf16x8 a[4], b[2];
    #pragma unroll
    for (int r = 0; r < 4; ++r)
      a[r] = *reinterpret_cast<const bf16x8*>(&sA4[(((kk - 4) << 2) + r)*64 + l]);
    #pragma unroll
    for (int c = 0; c < 2; ++c)
      b[c] = *reinterpret_cast<const bf16x8*>(B1p + ((((kk << 3) + (w << 1) + c) << 6) + l)*8);
    #pragma unroll
    for (int r = 0; r < 4; ++r)
      #pragma unroll
      for (int c = 0; c < 2; ++c)
        acc[r][c] = mfma_b16(a[r], b[c], acc[r][c]);
  }
  __syncthreads();

  #pragma unroll
  for (int r = 0; r < 4; ++r){
    #pragma unroll
    for (int i = 0; i < 4; ++i){
      unsigned d = pk_bf16(silu_f(acc[r][0][i] + bb1.x), silu_f(acc[r][1][i] + bb1.y));
      int a0 = ((((w << 2) + r) << 10) | ((ll >> 2) << 8) | (lw << 6) | (i << 4) | ((ll & 3) << 2));
      *reinterpret_cast<unsigned*>(sA + SWZ(a0)) = d;
    }
  }
  __syncthreads();

  f32x4 acc2[4][2] = {};
  #pragma unroll
  for (int kk = 0; kk < 4; ++kk){
    bf16x8 a[4], b[2];
    #pragma unroll
    for (int r = 0; r < 4; ++r){
      int a0 = ((((kk << 2) + r) << 10) | (l << 4));
      a[r] = *reinterpret_cast<const bf16x8*>(sA + SWZ(a0));
    }
    #pragma unroll
    for (int c = 0; c < 2; ++c)
      b[c] = *reinterpret_cast<const bf16x8*>(B2p + ((((kk << 3) + (w << 1) + c) << 6) + l)*8);
    #pragma unroll
    for (int r = 0; r < 4; ++r)
      #pragma unroll
      for (int c = 0; c < 2; ++c)
        acc2[r][c] = mfma_b16(a[r], b[c], acc2[r][c]);
  }

  // final epilogue (paired): residual f32 + bf16 mirror
  {
    const float2 bb2 = *reinterpret_cast<const float2*>(bias2 + q2);
    #pragma unroll
    for (int r = 0; r < 4; ++r){
      #pragma unroll
      for (int i = 0; i < 4; ++i){
        int rt = (r << 4) + (lw << 2) + i;
        int n = n0 + rt;
        if (n < NN){
          float2 ho = *reinterpret_cast<const float2*>(hf + (size_t)n*HD + q2);
          float h0 = ho.x + acc2[r][0][i] + bb2.x;
          float h1 = ho.y + acc2[r][1][i] + bb2.y;
          *reinterpret_cast<float2*>(hf + (size_t)n*HD + q2) = make_float2(h0, h1);
          *reinterpret_cast<unsigned*>(hb + (size_t)n*HD + q2) = pk_bf16(h0, h1);
        }
      }
    }
  }
}

// ---- decoder: out = silu(h @ dw1 + db1) @ dw2 + db2 ----
__global__ __launch_bounds__(256) void dec_kernel(
    const unsigned short* __restrict__ hb, const unsigned short* __restrict__ D1p,
    const float* __restrict__ db1, const float* __restrict__ dw2,
    const float* __restrict__ db2, float* __restrict__ outp)
{
  __shared__ alignas(128) char sA[1024*16];
  uint4* sA4 = reinterpret_cast<uint4*>(sA);
  __shared__ float sT[64*133];
  const int t = threadIdx.x;
  const int n0 = blockIdx.x << 6;
  {
    const int nl_ = t >> 2, p = t & 3;
    const int n = n0 + nl_;
    const bool valid = (n < NN);
    const int nc = valid ? n : 0;
    const uint4* src = reinterpret_cast<const uint4*>(hb + (size_t)nc*HD);
    const int base16 = ((nl_ >> 4) << 6) + (nl_ & 15);
    #pragma unroll
    for (int c = 0; c < 4; ++c){
      int q = (p << 2) + c;
      uint4 d = valid ? src[q] : make_uint4(0,0,0,0);
      sA4[base16 + ((q >> 2) << 8) + ((q & 3) << 4)] = d;
    }
  }
  __syncthreads();

  const int w = t >> 6, l = t & 63;
  const int lw = l >> 4, ll = l & 15;

  f32x4 acc[4][2] = {};
  #pragma unroll
  for (int kk = 0; kk < 4; ++kk){
    bf16x8 a[4], b[2];
    #pragma unroll
    for (int r = 0; r < 4; ++r)
      a[r] = *reinterpret_cast<const bf16x8*>(&sA4[((kk << 2) + r)*64 + l]);
    #pragma unroll
    for (int c = 0; c < 2; ++c)
      b[c] = *reinterpret_cast<const bf16x8*>(D1p + ((((kk << 3) + (w << 1) + c) << 6) + l)*8);
    #pragma unroll
    for (int r = 0; r < 4; ++r)
      #pragma unroll
      for (int c = 0; c < 2; ++c)
        acc[r][c] = mfma_b16(a[r], b[c], acc[r][c]);
  }
  #pragma unroll
  for (int r = 0; r < 4; ++r){
    #pragma unroll
    for (int i = 0; i < 4; ++i){
      int rt = (r << 4) + (lw << 2) + i;
      #pragma unroll
      for (int c = 0; c < 2; ++c){
        int col = (w << 5) + (c << 4) + ll;
        sT[rt*133 + col] = silu_f(acc[r][c][i] + db1[col]);
      }
    }
  }
  __syncthreads();
  if (t < 192){
    int rr = t & 63, cc = t >> 6;
    int n = n0 + rr;
    if (n < NN){
      float s = db2[cc];
      #pragma unroll 8
      for (int k = 0; k < HD; ++k) s += sT[rr*133 + k]*dw2[k*3 + cc];
      outp[(size_t)n*3 + cc] = s;
    }
  }
}

static inline char* alignup(char* p, size_t a){ return (char*)(((uintptr_t)p + a - 1) & ~(a - 1)); }

extern "C" void kernel_launch(void* const* d_in, const int* in_sizes, int n_in,
                              void* d_out, int out_size, void* d_ws, size_t ws_size,
                              hipStream_t stream)
{
  const float* loc  = (const float*)d_in[0];
  const float* vel  = (const float*)d_in[1];
  const float* ea   = (const float*)d_in[2];
  const int*   row  = (const int*)d_in[3];
  const int*   col  = (const int*)d_in[4];
  const float* embw = (const float*)d_in[5];
  const float* embb = (const float*)d_in[6];
  const float* ew1  = (const float*)d_in[7];
  const float* eb1  = (const float*)d_in[8];
  const float* ew2  = (const float*)d_in[9];
  const float* eb2  = (const float*)d_in[10];
  const float* nw1  = (const float*)d_in[11];
  const float* nb1  = (const float*)d_in[12];
  const float* nw2  = (const float*)d_in[13];
  const float* nb2  = (const float*)d_in[14];
  const float* dw1  = (const float*)d_in[15];
  const float* db1  = (const float*)d_in[16];
  const float* dw2  = (const float*)d_in[17];
  const float* db2  = (const float*)d_in[18];

  char* p = (char*)d_ws;
  float* hf = (float*)p;                       p += (size_t)NN*HD*4;
  unsigned short* hbuf = (unsigned short*)p;   p += (size_t)NN*HD*2;
  unsigned short* aggb = (unsigned short*)p;   p += (size_t)NN*HD*2;
  int* cnt = (int*)p;                          p += (size_t)NN*4;
  int* cur = (int*)p;                          p += (size_t)NN*4;
  int* bsum = (int*)p;                         p += (size_t)256*4;   p = alignup(p, 256);
  int* row_s = (int*)p;                        p += (size_t)NE*4;
  int* col_s = (int*)p;                        p += (size_t)NE*4;
  float* ea_s = (float*)p;                     p += (size_t)NE*2*4;
  unsigned short* ew1p = (unsigned short*)p;   p += (size_t)NL*256*HD*2;
  unsigned short* ew2p = (unsigned short*)p;   p += (size_t)NL*128*HD*2;
  unsigned short* nw1p = (unsigned short*)p;   p += (size_t)NL*256*HD*2;
  unsigned short* nw2p = (unsigned short*)p;   p += (size_t)NL*128*HD*2;
  unsigned short* dw1p = (unsigned short*)p;   p += (size_t)128*HD*2;

  // CSR build (parallel scan; once per launch)
  hipMemsetAsync(cnt, 0, (size_t)NN*4, stream);
  count_kernel<<<(NE + 255)/256, 256, 0, stream>>>(row, cnt);
  blocksum_kernel<<<NSCB, 256, 0, stream>>>(cnt, bsum);
  scanb_kernel<<<1, 256, 0, stream>>>(bsum);
  offsets_kernel<<<NSCB, 256, 0, stream>>>(cnt, bsum, cur);
  assign_kernel<<<(NE + 255)/256, 256, 0, stream>>>(row, col, ea, cur, row_s, col_s, ea_s);

  pack_b<<<dim3(128, NL), 256, 0, stream>>>(ew1, ew1p, 256, 256, 258*HD, 1);  // ea rows via epilogue
  pack_b<<<dim3(64,  NL), 256, 0, stream>>>(ew2, ew2p, 128, 128, 128*HD, 1);  // paired -> pk atomics
  pack_b<<<dim3(128, NL), 256, 0, stream>>>(nw1, nw1p, 256, 256, 256*HD, 1);
  pack_b<<<dim3(64,  NL), 256, 0, stream>>>(nw2, nw2p, 128, 128, 128*HD, 1);
  pack_b<<<dim3(64,  1 ), 256, 0, stream>>>(dw1, dw1p, 128, 128, 0, 0);

  emb_kernel<<<(NN*HD)/256, 256, 0, stream>>>(loc, vel, embw, embb, hf, hbuf);

  hipMemsetAsync(aggb, 0, (size_t)NN*HD*2, stream);   // layer 0; later layers zeroed by node_kernel
  for (int i = 0; i < NL; ++i){
    edge_kernel<<<NWG_E, 256, 0, stream>>>(hbuf, row_s, col_s, ea_s,
        ew1p + (size_t)i*256*HD, ew2p + (size_t)i*128*HD,
        eb1 + i*HD, eb2 + i*HD,
        ew1 + (size_t)i*258*HD + 256*HD, aggb);
    node_kernel<<<(NN + 63)/64, 256, 0, stream>>>(hbuf, aggb,
        nw1p + (size_t)i*256*HD, nw2p + (size_t)i*128*HD,
        nb1 + i*HD, nb2 + i*HD, hf);
  }

  dec_kernel<<<(NN + 63)/64, 256, 0, stream>>>(hbuf, dw1p, db1, dw2, db2, (float*)d_out);
}